// Round 6
// baseline (1253.830 us; speedup 1.0000x reference)
//
#include <hip/hip_runtime.h>

#define N_NODES 20000
#define N_EDGES 320000
#define X_DIM 128
#define EDGE_DIM 64
#define HIDDEN 256
#define N_GRAPHS 64
#define LAYERS 3

#define NPB 8     // nodes per block (node_proj)
#define EB 32     // edges per tile (edge_mfma)
#define ET 4      // tiles per block (edge_mfma)
#define PSPLIT 8  // blocks per graph (pool)
#define NBLK ((N_NODES + 255) / 256)   // 79 scan blocks

typedef __attribute__((ext_vector_type(8))) short short8;
typedef __attribute__((ext_vector_type(4))) float floatx4;

__device__ __forceinline__ unsigned short f2bf(float f) {
    union { float f; unsigned u; } v; v.f = f;
    return (unsigned short)((v.u + 0x7FFFu + ((v.u >> 16) & 1u)) >> 16);
}
__device__ __forceinline__ float bf2f(unsigned short u) {
    return __uint_as_float(((unsigned)u) << 16);
}

// ---------------- CSR build + pre-pass (once per launch) ----------------

__global__ __launch_bounds__(256) void deg_kernel(const int* __restrict__ ei,
                                                  int* __restrict__ deg)
{
    int e = blockIdx.x * 256 + threadIdx.x;
    if (e < N_EDGES) atomicAdd(&deg[ei[N_EDGES + e]], 1);
}

__global__ __launch_bounds__(256) void pscan_kernel(const int* __restrict__ deg,
                                                    int* __restrict__ rp,
                                                    int* __restrict__ bsum)
{
    __shared__ int buf[256];
    const int t = threadIdx.x;
    const int i = blockIdx.x * 256 + t;
    int v = (i < N_NODES) ? deg[i] : 0;
    buf[t] = v;
    __syncthreads();
    for (int off = 1; off < 256; off <<= 1) {
        int a = (t >= off) ? buf[t - off] : 0;
        __syncthreads();
        buf[t] += a;
        __syncthreads();
    }
    if (i < N_NODES) rp[i] = buf[t] - v;
    if (t == 255) bsum[blockIdx.x] = buf[255];
}

__global__ __launch_bounds__(128) void bscan_kernel(const int* __restrict__ bsum,
                                                    int* __restrict__ boff)
{
    __shared__ int buf[128];
    const int t = threadIdx.x;
    int v = (t < NBLK) ? bsum[t] : 0;
    buf[t] = v;
    __syncthreads();
    for (int off = 1; off < 128; off <<= 1) {
        int a = (t >= off) ? buf[t - off] : 0;
        __syncthreads();
        buf[t] += a;
        __syncthreads();
    }
    if (t < NBLK) boff[t] = buf[t] - v;
}

__global__ __launch_bounds__(256) void addoff_kernel(int* __restrict__ rp,
                                                     const int* __restrict__ boff)
{
    const int i = blockIdx.x * 256 + threadIdx.x;
    if (i < N_NODES) rp[i] += boff[blockIdx.x];
    if (i == 0) rp[N_NODES] = N_EDGES;
}

__global__ __launch_bounds__(256) void scatter_kernel(const int* __restrict__ ei,
                                                      const int* __restrict__ rp,
                                                      int* __restrict__ cursor,
                                                      int* __restrict__ perm)
{
    const int e = blockIdx.x * 256 + threadIdx.x;
    if (e < N_EDGES) {
        const int d = ei[N_EDGES + e];
        const int pos = atomicAdd(&cursor[d], 1);
        perm[rp[d] + pos] = e;
    }
}

// dst-sorted bf16 edge attrs + sorted src/dst index arrays
__global__ __launch_bounds__(256) void permute_kernel(
    const float* __restrict__ ea, const int* __restrict__ ei,
    const int* __restrict__ perm, unsigned short* __restrict__ eab,
    int* __restrict__ srcs, int* __restrict__ dsts)
{
    const int tid = blockIdx.x * 256 + threadIdx.x;
    const int e = tid >> 3, seg = tid & 7;
    const int p = perm[e];
    const float* sp = ea + (size_t)p * EDGE_DIM + seg * 8;
    const float4 v0 = *(const float4*)sp;
    const float4 v1 = *(const float4*)(sp + 4);
    short8 o;
    o[0] = (short)f2bf(v0.x); o[1] = (short)f2bf(v0.y);
    o[2] = (short)f2bf(v0.z); o[3] = (short)f2bf(v0.w);
    o[4] = (short)f2bf(v1.x); o[5] = (short)f2bf(v1.y);
    o[6] = (short)f2bf(v1.z); o[7] = (short)f2bf(v1.w);
    *(short8*)(eab + (size_t)e * EDGE_DIM + seg * 8) = o;
    if (seg == 0) { srcs[e] = ei[p]; dsts[e] = ei[N_EDGES + p]; }
}

// W [K][256] fp32 -> bf16 MFMA B-fragment order
__global__ __launch_bounds__(256) void swizzle_kernel(const float* __restrict__ W,
                                                      unsigned short* __restrict__ out,
                                                      int KK)
{
    const int i = blockIdx.x * 256 + threadIdx.x;
    if (i >= 8192 * KK) return;
    const int j = i & 7, lane = (i >> 3) & 63, rem = i >> 9;
    const int kk = rem % KK, rem2 = rem / KK, nt = rem2 & 3, wvv = rem2 >> 2;
    const int n = wvv * 64 + nt * 16 + (lane & 15);
    const int k = kk * 32 + (lane >> 4) * 8 + j;
    out[i] = f2bf(W[k * HIDDEN + n]);
}

// ---------------- model kernels ----------------

// h[i] = x[i] @ xW + xb (fp32); also writes hbf and zeroes z
__global__ __launch_bounds__(256) void node_proj_kernel(
    const float* __restrict__ x, const float* __restrict__ W,
    const float* __restrict__ b, float* __restrict__ h,
    unsigned short* __restrict__ hbf, float* __restrict__ z)
{
    const int t = threadIdx.x;
    const int row0 = blockIdx.x * NPB;
    __shared__ float xs[NPB][X_DIM];
    for (int idx = t; idx < NPB * X_DIM; idx += 256)
        xs[idx / X_DIM][idx % X_DIM] = x[(size_t)row0 * X_DIM + idx];
    __syncthreads();
    float acc[NPB];
    const float bt = b[t];
#pragma unroll
    for (int r = 0; r < NPB; r++) acc[r] = bt;
    for (int k = 0; k < X_DIM; k++) {
        const float wv = W[k * HIDDEN + t];
#pragma unroll
        for (int r = 0; r < NPB; r++) acc[r] += xs[r][k] * wv;
    }
#pragma unroll
    for (int r = 0; r < NPB; r++) {
        const size_t idx = (size_t)(row0 + r) * HIDDEN + t;
        h[idx] = acc[r];
        hbf[idx] = f2bf(acc[r]);
        z[idx] = 0.f;
    }
}

// edge phase: z[dst] += relu(hbf[src] + eab@eW + eb), edges dst-sorted.
// bf16 msg tile (17KB LDS -> 8 blocks/CU); segmented sum carried across tiles.
__global__ __launch_bounds__(256, 8) void edge_mfma_kernel(
    const unsigned short* __restrict__ eab, const int* __restrict__ srcs,
    const int* __restrict__ dsts, const unsigned short* __restrict__ Ws,
    const float* __restrict__ b, const unsigned short* __restrict__ hbf,
    float* __restrict__ z)
{
    const int t = threadIdx.x;
    const int lane = t & 63, wv = t >> 6, q = lane >> 4, m15 = lane & 15;
    __shared__ unsigned short msg[EB][264];   // bf16, stride 528B -> ~conflict-free
    __shared__ int s_src[2][EB], s_dst[2][EB];

    // loop-invariant B fragments (8 x 16B coalesced loads)
    short8 bfr[4][2];
#pragma unroll
    for (int nt = 0; nt < 4; nt++)
#pragma unroll
        for (int kk = 0; kk < 2; kk++)
            bfr[nt][kk] = *(const short8*)(Ws + ((((wv * 4 + nt) * 2 + kk) * 64) + lane) * 8);
    const float bt = b[t];

    // preload tile 0 indices
    if (t < EB) {
        const int e0 = blockIdx.x * ET * EB;
        s_src[0][t] = srcs[e0 + t];
        s_dst[0][t] = dsts[e0 + t];
    }
    __syncthreads();

    // segmented-sum state carried across tiles (edges in block are consecutive, sorted)
    float s = 0.f;
    int prev = s_dst[0][0];

    for (int tile = 0; tile < ET; tile++) {
        const int cur = tile & 1;
        const int e0 = (blockIdx.x * ET + tile) * EB;

        // 1. prefetch h rows for this tile into registers
        unsigned short hv[EB];
#pragma unroll
        for (int e = 0; e < EB; e++)
            hv[e] = hbf[(size_t)s_src[cur][e] * HIDDEN + t];

        // 2. prefetch next tile's indices into the other buffer
        if (tile + 1 < ET && t < EB) {
            s_src[1 - cur][t] = srcs[e0 + EB + t];
            s_dst[1 - cur][t] = dsts[e0 + EB + t];
        }

        // 3. MFMA: proj = eab[tile] @ eW
        floatx4 acc[2][4];
#pragma unroll
        for (int mt = 0; mt < 2; mt++)
#pragma unroll
            for (int nt = 0; nt < 4; nt++)
                acc[mt][nt] = (floatx4){0.f, 0.f, 0.f, 0.f};
#pragma unroll
        for (int kk = 0; kk < 2; kk++) {
            const short8 a0 = *(const short8*)(eab + (size_t)(e0 + m15) * EDGE_DIM + kk * 32 + q * 8);
            const short8 a1 = *(const short8*)(eab + (size_t)(e0 + 16 + m15) * EDGE_DIM + kk * 32 + q * 8);
#pragma unroll
            for (int nt = 0; nt < 4; nt++) {
                acc[0][nt] = __builtin_amdgcn_mfma_f32_16x16x32_bf16(a0, bfr[nt][kk], acc[0][nt], 0, 0, 0);
                acc[1][nt] = __builtin_amdgcn_mfma_f32_16x16x32_bf16(a1, bfr[nt][kk], acc[1][nt], 0, 0, 0);
            }
        }
        // C layout: edge = mt*16 + q*4 + r, ch = wv*64 + nt*16 + m15
#pragma unroll
        for (int mt = 0; mt < 2; mt++)
#pragma unroll
            for (int nt = 0; nt < 4; nt++)
#pragma unroll
                for (int r = 0; r < 4; r++)
                    msg[mt * 16 + q * 4 + r][wv * 64 + nt * 16 + m15] = f2bf(acc[mt][nt][r]);
        __syncthreads();

        // 4. epilogue: thread t owns channel t; segmented sum over sorted dst
#pragma unroll
        for (int e = 0; e < EB; e++) {
            const int d = s_dst[cur][e];
            if (d != prev) {
                atomicAdd(&z[(size_t)prev * HIDDEN + t], s);
                s = 0.f; prev = d;
            }
            const float m = bf2f(msg[e][t]) + bt + bf2f(hv[e]);
            s += m > 0.f ? m : 0.f;
        }
        __syncthreads();   // msg/s_dst reuse next tile
    }
    atomicAdd(&z[(size_t)prev * HIDDEN + t], s);
}

// h = relu(relu((h+z)@W1+b1)@W2+b2) with bf16 MFMA; re-zeroes z, writes hbf
__global__ __launch_bounds__(256) void mlp_mfma_kernel(
    const unsigned short* __restrict__ W1s, const float* __restrict__ b1,
    const unsigned short* __restrict__ W2s, const float* __restrict__ b2,
    float* __restrict__ h, float* __restrict__ z, unsigned short* __restrict__ hbf)
{
    const int t = threadIdx.x;
    const int lane = t & 63, wv = t >> 6, q = lane >> 4, m15 = lane & 15;
    const int row0 = blockIdx.x * 32;
    __shared__ __align__(16) unsigned short zs[32][264];

    // stage A = bf16(h+z); zero z for next layer
#pragma unroll
    for (int r = 0; r < 32; r++) {
        const size_t idx = (size_t)(row0 + r) * HIDDEN + t;
        zs[r][t] = f2bf(h[idx] + z[idx]);
        z[idx] = 0.f;
    }
    __syncthreads();

    float b1v[4], b2v[4];
#pragma unroll
    for (int nt = 0; nt < 4; nt++) {
        const int c = wv * 64 + nt * 16 + m15;
        b1v[nt] = b1[c]; b2v[nt] = b2[c];
    }

    floatx4 acc[2][4];
#pragma unroll
    for (int mt = 0; mt < 2; mt++)
#pragma unroll
        for (int nt = 0; nt < 4; nt++)
            acc[mt][nt] = (floatx4){0.f, 0.f, 0.f, 0.f};

    // GEMM1
#pragma unroll
    for (int kk = 0; kk < 8; kk++) {
        short8 bfr[4];
#pragma unroll
        for (int nt = 0; nt < 4; nt++)
            bfr[nt] = *(const short8*)(W1s + ((((wv * 4 + nt) * 8 + kk) * 64) + lane) * 8);
        const short8 a0 = *(const short8*)&zs[m15][kk * 32 + q * 8];
        const short8 a1 = *(const short8*)&zs[16 + m15][kk * 32 + q * 8];
#pragma unroll
        for (int nt = 0; nt < 4; nt++) {
            acc[0][nt] = __builtin_amdgcn_mfma_f32_16x16x32_bf16(a0, bfr[nt], acc[0][nt], 0, 0, 0);
            acc[1][nt] = __builtin_amdgcn_mfma_f32_16x16x32_bf16(a1, bfr[nt], acc[1][nt], 0, 0, 0);
        }
    }
    __syncthreads();
    // relu(acc+b1) -> zs (bf16)
#pragma unroll
    for (int mt = 0; mt < 2; mt++)
#pragma unroll
        for (int nt = 0; nt < 4; nt++)
#pragma unroll
            for (int r = 0; r < 4; r++) {
                const int row = mt * 16 + q * 4 + r, c = wv * 64 + nt * 16 + m15;
                const float v = acc[mt][nt][r] + b1v[nt];
                zs[row][c] = f2bf(v > 0.f ? v : 0.f);
            }
    __syncthreads();

#pragma unroll
    for (int mt = 0; mt < 2; mt++)
#pragma unroll
        for (int nt = 0; nt < 4; nt++)
            acc[mt][nt] = (floatx4){0.f, 0.f, 0.f, 0.f};

    // GEMM2
#pragma unroll
    for (int kk = 0; kk < 8; kk++) {
        short8 bfr[4];
#pragma unroll
        for (int nt = 0; nt < 4; nt++)
            bfr[nt] = *(const short8*)(W2s + ((((wv * 4 + nt) * 8 + kk) * 64) + lane) * 8);
        const short8 a0 = *(const short8*)&zs[m15][kk * 32 + q * 8];
        const short8 a1 = *(const short8*)&zs[16 + m15][kk * 32 + q * 8];
#pragma unroll
        for (int nt = 0; nt < 4; nt++) {
            acc[0][nt] = __builtin_amdgcn_mfma_f32_16x16x32_bf16(a0, bfr[nt], acc[0][nt], 0, 0, 0);
            acc[1][nt] = __builtin_amdgcn_mfma_f32_16x16x32_bf16(a1, bfr[nt], acc[1][nt], 0, 0, 0);
        }
    }
    // epilogue: h = relu(acc+b2), hbf = bf16(h)
#pragma unroll
    for (int mt = 0; mt < 2; mt++)
#pragma unroll
        for (int nt = 0; nt < 4; nt++)
#pragma unroll
            for (int r = 0; r < 4; r++) {
                const int row = mt * 16 + q * 4 + r, c = wv * 64 + nt * 16 + m15;
                float v = acc[mt][nt][r] + b2v[nt];
                v = v > 0.f ? v : 0.f;
                const size_t idx = (size_t)(row0 + row) * HIDDEN + c;
                h[idx] = v;
                hbf[idx] = f2bf(v);
            }
}

// parallel mean-pool partials: PSPLIT blocks per graph, atomicAdd into gsum
__global__ __launch_bounds__(256) void pool_kernel(
    const float* __restrict__ h, const int* __restrict__ bid,
    float* __restrict__ gsum)
{
    const int g = blockIdx.x / PSPLIT;
    const int part = blockIdx.x % PSPLIT;
    const int t = threadIdx.x;
    int lo = 0, hi = N_NODES;
    while (lo < hi) { int mid = (lo + hi) >> 1; if (bid[mid] < g) lo = mid + 1; else hi = mid; }
    const int start = lo;
    hi = N_NODES;
    while (lo < hi) { int mid = (lo + hi) >> 1; if (bid[mid] < g + 1) lo = mid + 1; else hi = mid; }
    const int end = lo;
    const int len = end - start;
    const int chunk = (len + PSPLIT - 1) / PSPLIT;
    const int s0 = start + part * chunk;
    const int s1 = min(s0 + chunk, end);
    if (s0 >= s1) return;
    float s = 0.f;
    for (int i = s0; i < s1; i++) s += h[(size_t)i * HIDDEN + t];
    atomicAdd(&gsum[g * HIDDEN + t], s);
}

// out = normalize(relu((gsum/cnt)@oW1+ob1)@oW2+ob2)
__global__ __launch_bounds__(256) void head_kernel(
    const float* __restrict__ gsum, const int* __restrict__ bid,
    const float* __restrict__ W1, const float* __restrict__ b1,
    const float* __restrict__ W2, const float* __restrict__ b2,
    float* __restrict__ out)
{
    const int g = blockIdx.x;
    const int t = threadIdx.x;
    __shared__ float gs[HIDDEN];
    __shared__ float t1[HIDDEN];
    __shared__ float red[256];
    int lo = 0, hi = N_NODES;
    while (lo < hi) { int mid = (lo + hi) >> 1; if (bid[mid] < g) lo = mid + 1; else hi = mid; }
    const int start = lo;
    hi = N_NODES;
    while (lo < hi) { int mid = (lo + hi) >> 1; if (bid[mid] < g + 1) lo = mid + 1; else hi = mid; }
    float cnt = (float)(lo - start);
    cnt = cnt > 1.f ? cnt : 1.f;
    gs[t] = gsum[g * HIDDEN + t] / cnt;
    __syncthreads();
    float acc = b1[t];
    for (int k = 0; k < HIDDEN; k++) acc += gs[k] * W1[k * HIDDEN + t];
    t1[t] = acc > 0.f ? acc : 0.f;
    __syncthreads();
    float acc2 = b2[t];
    for (int k = 0; k < HIDDEN; k++) acc2 += t1[k] * W2[k * HIDDEN + t];
    red[t] = acc2 * acc2;
    __syncthreads();
    for (int s = 128; s > 0; s >>= 1) {
        if (t < s) red[t] += red[t + s];
        __syncthreads();
    }
    float norm = sqrtf(red[0]);
    norm = norm > 1e-12f ? norm : 1e-12f;
    out[g * HIDDEN + t] = acc2 / norm;
}

extern "C" void kernel_launch(void* const* d_in, const int* in_sizes, int n_in,
                              void* d_out, int out_size, void* d_ws, size_t ws_size,
                              hipStream_t stream)
{
    const float* x   = (const float*)d_in[0];
    const int*   ei  = (const int*)d_in[1];
    const float* ea  = (const float*)d_in[2];
    const int*   bid = (const int*)d_in[3];
    const float* xW  = (const float*)d_in[4];
    const float* xb  = (const float*)d_in[5];
    const float* eW  = (const float*)d_in[6];
    const float* eb  = (const float*)d_in[7];
    const float* W1  = (const float*)d_in[8];
    const float* b1  = (const float*)d_in[9];
    const float* W2  = (const float*)d_in[10];
    const float* b2  = (const float*)d_in[11];
    const float* oW1 = (const float*)d_in[12];
    const float* ob1 = (const float*)d_in[13];
    const float* oW2 = (const float*)d_in[14];
    const float* ob2 = (const float*)d_in[15];
    float* out = (float*)d_out;

    // workspace layout (256B-aligned chunks)
    char* p = (char*)d_ws;
    auto alloc = [&](size_t bytes) { char* r = p; p += (bytes + 255) & ~(size_t)255; return r; };
    float* h     = (float*)alloc((size_t)N_NODES * HIDDEN * 4);
    float* z     = (float*)alloc((size_t)N_NODES * HIDDEN * 4);
    float* gpool = (float*)alloc((size_t)N_GRAPHS * HIDDEN * 4);
    int* deg     = (int*)alloc(N_NODES * 4);
    int* rowptr  = (int*)alloc((N_NODES + 1) * 4);
    int* cursor  = (int*)alloc(N_NODES * 4);
    int* bsum    = (int*)alloc(NBLK * 4);
    int* boff    = (int*)alloc(NBLK * 4);
    int* perm    = (int*)alloc((size_t)N_EDGES * 4);
    int* srcs    = (int*)alloc((size_t)N_EDGES * 4);
    int* dsts    = (int*)alloc((size_t)N_EDGES * 4);
    unsigned short* hbf = (unsigned short*)alloc((size_t)N_NODES * HIDDEN * 2);
    unsigned short* eab = (unsigned short*)alloc((size_t)N_EDGES * EDGE_DIM * 2);
    unsigned short* eWs = (unsigned short*)alloc((size_t)LAYERS * EDGE_DIM * HIDDEN * 2);
    unsigned short* W1s = (unsigned short*)alloc((size_t)LAYERS * HIDDEN * HIDDEN * 2);
    unsigned short* W2s = (unsigned short*)alloc((size_t)LAYERS * HIDDEN * HIDDEN * 2);

    // CSR build + dst-sorted bf16 edge data (reused across layers)
    hipMemsetAsync(deg, 0, N_NODES * sizeof(int), stream);
    hipMemsetAsync(cursor, 0, N_NODES * sizeof(int), stream);
    hipMemsetAsync(gpool, 0, N_GRAPHS * HIDDEN * sizeof(float), stream);
    deg_kernel<<<(N_EDGES + 255) / 256, 256, 0, stream>>>(ei, deg);
    pscan_kernel<<<NBLK, 256, 0, stream>>>(deg, rowptr, bsum);
    bscan_kernel<<<1, 128, 0, stream>>>(bsum, boff);
    addoff_kernel<<<NBLK, 256, 0, stream>>>(rowptr, boff);
    scatter_kernel<<<(N_EDGES + 255) / 256, 256, 0, stream>>>(ei, rowptr, cursor, perm);
    permute_kernel<<<(N_EDGES * 8) / 256, 256, 0, stream>>>(ea, ei, perm, eab, srcs, dsts);
    for (int l = 0; l < LAYERS; l++) {
        swizzle_kernel<<<64, 256, 0, stream>>>(eW + (size_t)l * EDGE_DIM * HIDDEN,
                                               eWs + (size_t)l * EDGE_DIM * HIDDEN, 2);
        swizzle_kernel<<<256, 256, 0, stream>>>(W1 + (size_t)l * HIDDEN * HIDDEN,
                                                W1s + (size_t)l * HIDDEN * HIDDEN, 8);
        swizzle_kernel<<<256, 256, 0, stream>>>(W2 + (size_t)l * HIDDEN * HIDDEN,
                                                W2s + (size_t)l * HIDDEN * HIDDEN, 8);
    }

    node_proj_kernel<<<N_NODES / NPB, 256, 0, stream>>>(x, xW, xb, h, hbf, z);
    for (int l = 0; l < LAYERS; l++) {
        edge_mfma_kernel<<<N_EDGES / (EB * ET), 256, 0, stream>>>(
            eab, srcs, dsts, eWs + (size_t)l * EDGE_DIM * HIDDEN,
            eb + l * HIDDEN, hbf, z);
        mlp_mfma_kernel<<<N_NODES / 32, 256, 0, stream>>>(
            W1s + (size_t)l * HIDDEN * HIDDEN, b1 + l * HIDDEN,
            W2s + (size_t)l * HIDDEN * HIDDEN, b2 + l * HIDDEN, h, z, hbf);
    }
    pool_kernel<<<N_GRAPHS * PSPLIT, 256, 0, stream>>>(h, bid, gpool);
    head_kernel<<<N_GRAPHS, 256, 0, stream>>>(gpool, bid, oW1, ob1, oW2, ob2, out);
}

// Round 7
// 596.373 us; speedup vs baseline: 2.1024x; 2.1024x over previous
//
#include <hip/hip_runtime.h>

#define N_NODES 20000
#define N_EDGES 320000
#define X_DIM 128
#define EDGE_DIM 64
#define HIDDEN 256
#define N_GRAPHS 64
#define LAYERS 3

#define NPB 8     // nodes per block (node_proj)
#define EB 32     // edges per tile (edge_mfma)
#define ET 4      // tiles per block (edge_mfma)
#define PSPLIT 8  // blocks per graph (pool)
#define NBLK ((N_NODES + 255) / 256)   // 79 scan blocks

typedef __attribute__((ext_vector_type(8))) short short8;
typedef __attribute__((ext_vector_type(4))) float floatx4;

__device__ __forceinline__ unsigned short f2bf(float f) {
    union { float f; unsigned u; } v; v.f = f;
    return (unsigned short)((v.u + 0x7FFFu + ((v.u >> 16) & 1u)) >> 16);
}
__device__ __forceinline__ float bf2f(unsigned short u) {
    return __uint_as_float(((unsigned)u) << 16);
}

// ---------------- CSR build + pre-pass (once per launch) ----------------

__global__ __launch_bounds__(256) void deg_kernel(const int* __restrict__ ei,
                                                  int* __restrict__ deg)
{
    int e = blockIdx.x * 256 + threadIdx.x;
    if (e < N_EDGES) atomicAdd(&deg[ei[N_EDGES + e]], 1);
}

__global__ __launch_bounds__(256) void pscan_kernel(const int* __restrict__ deg,
                                                    int* __restrict__ rp,
                                                    int* __restrict__ bsum)
{
    __shared__ int buf[256];
    const int t = threadIdx.x;
    const int i = blockIdx.x * 256 + t;
    int v = (i < N_NODES) ? deg[i] : 0;
    buf[t] = v;
    __syncthreads();
    for (int off = 1; off < 256; off <<= 1) {
        int a = (t >= off) ? buf[t - off] : 0;
        __syncthreads();
        buf[t] += a;
        __syncthreads();
    }
    if (i < N_NODES) rp[i] = buf[t] - v;
    if (t == 255) bsum[blockIdx.x] = buf[255];
}

__global__ __launch_bounds__(128) void bscan_kernel(const int* __restrict__ bsum,
                                                    int* __restrict__ boff)
{
    __shared__ int buf[128];
    const int t = threadIdx.x;
    int v = (t < NBLK) ? bsum[t] : 0;
    buf[t] = v;
    __syncthreads();
    for (int off = 1; off < 128; off <<= 1) {
        int a = (t >= off) ? buf[t - off] : 0;
        __syncthreads();
        buf[t] += a;
        __syncthreads();
    }
    if (t < NBLK) boff[t] = buf[t] - v;
}

__global__ __launch_bounds__(256) void addoff_kernel(int* __restrict__ rp,
                                                     const int* __restrict__ boff)
{
    const int i = blockIdx.x * 256 + threadIdx.x;
    if (i < N_NODES) rp[i] += boff[blockIdx.x];
    if (i == 0) rp[N_NODES] = N_EDGES;
}

__global__ __launch_bounds__(256) void scatter_kernel(const int* __restrict__ ei,
                                                      const int* __restrict__ rp,
                                                      int* __restrict__ cursor,
                                                      int* __restrict__ perm)
{
    const int e = blockIdx.x * 256 + threadIdx.x;
    if (e < N_EDGES) {
        const int d = ei[N_EDGES + e];
        const int pos = atomicAdd(&cursor[d], 1);
        perm[rp[d] + pos] = e;
    }
}

// dst-sorted bf16 edge attrs + sorted src/dst index arrays
__global__ __launch_bounds__(256) void permute_kernel(
    const float* __restrict__ ea, const int* __restrict__ ei,
    const int* __restrict__ perm, unsigned short* __restrict__ eab,
    int* __restrict__ srcs, int* __restrict__ dsts)
{
    const int tid = blockIdx.x * 256 + threadIdx.x;
    const int e = tid >> 3, seg = tid & 7;
    const int p = perm[e];
    const float* sp = ea + (size_t)p * EDGE_DIM + seg * 8;
    const float4 v0 = *(const float4*)sp;
    const float4 v1 = *(const float4*)(sp + 4);
    short8 o;
    o[0] = (short)f2bf(v0.x); o[1] = (short)f2bf(v0.y);
    o[2] = (short)f2bf(v0.z); o[3] = (short)f2bf(v0.w);
    o[4] = (short)f2bf(v1.x); o[5] = (short)f2bf(v1.y);
    o[6] = (short)f2bf(v1.z); o[7] = (short)f2bf(v1.w);
    *(short8*)(eab + (size_t)e * EDGE_DIM + seg * 8) = o;
    if (seg == 0) { srcs[e] = ei[p]; dsts[e] = ei[N_EDGES + p]; }
}

// W [K][256] fp32 -> bf16 MFMA B-fragment order
__global__ __launch_bounds__(256) void swizzle_kernel(const float* __restrict__ W,
                                                      unsigned short* __restrict__ out,
                                                      int KK)
{
    const int i = blockIdx.x * 256 + threadIdx.x;
    if (i >= 8192 * KK) return;
    const int j = i & 7, lane = (i >> 3) & 63, rem = i >> 9;
    const int kk = rem % KK, rem2 = rem / KK, nt = rem2 & 3, wvv = rem2 >> 2;
    const int n = wvv * 64 + nt * 16 + (lane & 15);
    const int k = kk * 32 + (lane >> 4) * 8 + j;
    out[i] = f2bf(W[k * HIDDEN + n]);
}

// ---------------- model kernels ----------------

// h[i] = x[i] @ xW + xb (fp32); also writes hbf and zeroes z
__global__ __launch_bounds__(256) void node_proj_kernel(
    const float* __restrict__ x, const float* __restrict__ W,
    const float* __restrict__ b, float* __restrict__ h,
    unsigned short* __restrict__ hbf, float* __restrict__ z)
{
    const int t = threadIdx.x;
    const int row0 = blockIdx.x * NPB;
    __shared__ float xs[NPB][X_DIM];
    for (int idx = t; idx < NPB * X_DIM; idx += 256)
        xs[idx / X_DIM][idx % X_DIM] = x[(size_t)row0 * X_DIM + idx];
    __syncthreads();
    float acc[NPB];
    const float bt = b[t];
#pragma unroll
    for (int r = 0; r < NPB; r++) acc[r] = bt;
    for (int k = 0; k < X_DIM; k++) {
        const float wv = W[k * HIDDEN + t];
#pragma unroll
        for (int r = 0; r < NPB; r++) acc[r] += xs[r][k] * wv;
    }
#pragma unroll
    for (int r = 0; r < NPB; r++) {
        const size_t idx = (size_t)(row0 + r) * HIDDEN + t;
        h[idx] = acc[r];
        hbf[idx] = f2bf(acc[r]);
        z[idx] = 0.f;
    }
}

// edge phase: z[dst] += relu(hbf[src] + eab@eW + eb), edges dst-sorted.
// bf16 msg tile (17KB LDS); min-waves=4 (128 VGPR cap) -> no spill.
__global__ __launch_bounds__(256, 4) void edge_mfma_kernel(
    const unsigned short* __restrict__ eab, const int* __restrict__ srcs,
    const int* __restrict__ dsts, const unsigned short* __restrict__ Ws,
    const float* __restrict__ b, const unsigned short* __restrict__ hbf,
    float* __restrict__ z)
{
    const int t = threadIdx.x;
    const int lane = t & 63, wv = t >> 6, q = lane >> 4, m15 = lane & 15;
    __shared__ unsigned short msg[EB][264];   // bf16, stride 528B
    __shared__ int s_src[2][EB], s_dst[2][EB];

    // loop-invariant B fragments (8 x 16B coalesced loads)
    short8 bfr[4][2];
#pragma unroll
    for (int nt = 0; nt < 4; nt++)
#pragma unroll
        for (int kk = 0; kk < 2; kk++)
            bfr[nt][kk] = *(const short8*)(Ws + ((((wv * 4 + nt) * 2 + kk) * 64) + lane) * 8);
    const float bt = b[t];

    // preload tile 0 indices
    if (t < EB) {
        const int e0 = blockIdx.x * ET * EB;
        s_src[0][t] = srcs[e0 + t];
        s_dst[0][t] = dsts[e0 + t];
    }
    __syncthreads();

    // segmented-sum state carried across tiles (edges in block are consecutive, sorted)
    float s = 0.f;
    int prev = s_dst[0][0];

    for (int tile = 0; tile < ET; tile++) {
        const int cur = tile & 1;
        const int e0 = (blockIdx.x * ET + tile) * EB;

        // 1. prefetch h rows for this tile into registers
        unsigned short hv[EB];
#pragma unroll
        for (int e = 0; e < EB; e++)
            hv[e] = hbf[(size_t)s_src[cur][e] * HIDDEN + t];

        // 2. prefetch next tile's indices into the other buffer
        if (tile + 1 < ET && t < EB) {
            s_src[1 - cur][t] = srcs[e0 + EB + t];
            s_dst[1 - cur][t] = dsts[e0 + EB + t];
        }

        // 3. MFMA: proj = eab[tile] @ eW
        floatx4 acc[2][4];
#pragma unroll
        for (int mt = 0; mt < 2; mt++)
#pragma unroll
            for (int nt = 0; nt < 4; nt++)
                acc[mt][nt] = (floatx4){0.f, 0.f, 0.f, 0.f};
#pragma unroll
        for (int kk = 0; kk < 2; kk++) {
            const short8 a0 = *(const short8*)(eab + (size_t)(e0 + m15) * EDGE_DIM + kk * 32 + q * 8);
            const short8 a1 = *(const short8*)(eab + (size_t)(e0 + 16 + m15) * EDGE_DIM + kk * 32 + q * 8);
#pragma unroll
            for (int nt = 0; nt < 4; nt++) {
                acc[0][nt] = __builtin_amdgcn_mfma_f32_16x16x32_bf16(a0, bfr[nt][kk], acc[0][nt], 0, 0, 0);
                acc[1][nt] = __builtin_amdgcn_mfma_f32_16x16x32_bf16(a1, bfr[nt][kk], acc[1][nt], 0, 0, 0);
            }
        }
        // C layout: edge = mt*16 + q*4 + r, ch = wv*64 + nt*16 + m15
#pragma unroll
        for (int mt = 0; mt < 2; mt++)
#pragma unroll
            for (int nt = 0; nt < 4; nt++)
#pragma unroll
                for (int r = 0; r < 4; r++)
                    msg[mt * 16 + q * 4 + r][wv * 64 + nt * 16 + m15] = f2bf(acc[mt][nt][r]);
        __syncthreads();

        // 4. epilogue: thread t owns channel t; segmented sum over sorted dst
#pragma unroll
        for (int e = 0; e < EB; e++) {
            const int d = s_dst[cur][e];
            if (d != prev) {
                atomicAdd(&z[(size_t)prev * HIDDEN + t], s);
                s = 0.f; prev = d;
            }
            const float m = bf2f(msg[e][t]) + bt + bf2f(hv[e]);
            s += m > 0.f ? m : 0.f;
        }
        __syncthreads();   // msg/s_dst reuse next tile
    }
    atomicAdd(&z[(size_t)prev * HIDDEN + t], s);
}

// h = relu(relu((h+z)@W1+b1)@W2+b2) with bf16 MFMA; re-zeroes z, writes hbf
__global__ __launch_bounds__(256) void mlp_mfma_kernel(
    const unsigned short* __restrict__ W1s, const float* __restrict__ b1,
    const unsigned short* __restrict__ W2s, const float* __restrict__ b2,
    float* __restrict__ h, float* __restrict__ z, unsigned short* __restrict__ hbf)
{
    const int t = threadIdx.x;
    const int lane = t & 63, wv = t >> 6, q = lane >> 4, m15 = lane & 15;
    const int row0 = blockIdx.x * 32;
    __shared__ __align__(16) unsigned short zs[32][264];

    // stage A = bf16(h+z); zero z for next layer
#pragma unroll
    for (int r = 0; r < 32; r++) {
        const size_t idx = (size_t)(row0 + r) * HIDDEN + t;
        zs[r][t] = f2bf(h[idx] + z[idx]);
        z[idx] = 0.f;
    }
    __syncthreads();

    float b1v[4], b2v[4];
#pragma unroll
    for (int nt = 0; nt < 4; nt++) {
        const int c = wv * 64 + nt * 16 + m15;
        b1v[nt] = b1[c]; b2v[nt] = b2[c];
    }

    floatx4 acc[2][4];
#pragma unroll
    for (int mt = 0; mt < 2; mt++)
#pragma unroll
        for (int nt = 0; nt < 4; nt++)
            acc[mt][nt] = (floatx4){0.f, 0.f, 0.f, 0.f};

    // GEMM1
#pragma unroll
    for (int kk = 0; kk < 8; kk++) {
        short8 bfr[4];
#pragma unroll
        for (int nt = 0; nt < 4; nt++)
            bfr[nt] = *(const short8*)(W1s + ((((wv * 4 + nt) * 8 + kk) * 64) + lane) * 8);
        const short8 a0 = *(const short8*)&zs[m15][kk * 32 + q * 8];
        const short8 a1 = *(const short8*)&zs[16 + m15][kk * 32 + q * 8];
#pragma unroll
        for (int nt = 0; nt < 4; nt++) {
            acc[0][nt] = __builtin_amdgcn_mfma_f32_16x16x32_bf16(a0, bfr[nt], acc[0][nt], 0, 0, 0);
            acc[1][nt] = __builtin_amdgcn_mfma_f32_16x16x32_bf16(a1, bfr[nt], acc[1][nt], 0, 0, 0);
        }
    }
    __syncthreads();
    // relu(acc+b1) -> zs (bf16)
#pragma unroll
    for (int mt = 0; mt < 2; mt++)
#pragma unroll
        for (int nt = 0; nt < 4; nt++)
#pragma unroll
            for (int r = 0; r < 4; r++) {
                const int row = mt * 16 + q * 4 + r, c = wv * 64 + nt * 16 + m15;
                const float v = acc[mt][nt][r] + b1v[nt];
                zs[row][c] = f2bf(v > 0.f ? v : 0.f);
            }
    __syncthreads();

#pragma unroll
    for (int mt = 0; mt < 2; mt++)
#pragma unroll
        for (int nt = 0; nt < 4; nt++)
            acc[mt][nt] = (floatx4){0.f, 0.f, 0.f, 0.f};

    // GEMM2
#pragma unroll
    for (int kk = 0; kk < 8; kk++) {
        short8 bfr[4];
#pragma unroll
        for (int nt = 0; nt < 4; nt++)
            bfr[nt] = *(const short8*)(W2s + ((((wv * 4 + nt) * 8 + kk) * 64) + lane) * 8);
        const short8 a0 = *(const short8*)&zs[m15][kk * 32 + q * 8];
        const short8 a1 = *(const short8*)&zs[16 + m15][kk * 32 + q * 8];
#pragma unroll
        for (int nt = 0; nt < 4; nt++) {
            acc[0][nt] = __builtin_amdgcn_mfma_f32_16x16x32_bf16(a0, bfr[nt], acc[0][nt], 0, 0, 0);
            acc[1][nt] = __builtin_amdgcn_mfma_f32_16x16x32_bf16(a1, bfr[nt], acc[1][nt], 0, 0, 0);
        }
    }
    // epilogue: h = relu(acc+b2), hbf = bf16(h)
#pragma unroll
    for (int mt = 0; mt < 2; mt++)
#pragma unroll
        for (int nt = 0; nt < 4; nt++)
#pragma unroll
            for (int r = 0; r < 4; r++) {
                const int row = mt * 16 + q * 4 + r, c = wv * 64 + nt * 16 + m15;
                float v = acc[mt][nt][r] + b2v[nt];
                v = v > 0.f ? v : 0.f;
                const size_t idx = (size_t)(row0 + row) * HIDDEN + c;
                h[idx] = v;
                hbf[idx] = f2bf(v);
            }
}

// parallel mean-pool partials: PSPLIT blocks per graph, atomicAdd into gsum
__global__ __launch_bounds__(256) void pool_kernel(
    const float* __restrict__ h, const int* __restrict__ bid,
    float* __restrict__ gsum)
{
    const int g = blockIdx.x / PSPLIT;
    const int part = blockIdx.x % PSPLIT;
    const int t = threadIdx.x;
    int lo = 0, hi = N_NODES;
    while (lo < hi) { int mid = (lo + hi) >> 1; if (bid[mid] < g) lo = mid + 1; else hi = mid; }
    const int start = lo;
    hi = N_NODES;
    while (lo < hi) { int mid = (lo + hi) >> 1; if (bid[mid] < g + 1) lo = mid + 1; else hi = mid; }
    const int end = lo;
    const int len = end - start;
    const int chunk = (len + PSPLIT - 1) / PSPLIT;
    const int s0 = start + part * chunk;
    const int s1 = min(s0 + chunk, end);
    if (s0 >= s1) return;
    float s = 0.f;
    for (int i = s0; i < s1; i++) s += h[(size_t)i * HIDDEN + t];
    atomicAdd(&gsum[g * HIDDEN + t], s);
}

// out = normalize(relu((gsum/cnt)@oW1+ob1)@oW2+ob2)
__global__ __launch_bounds__(256) void head_kernel(
    const float* __restrict__ gsum, const int* __restrict__ bid,
    const float* __restrict__ W1, const float* __restrict__ b1,
    const float* __restrict__ W2, const float* __restrict__ b2,
    float* __restrict__ out)
{
    const int g = blockIdx.x;
    const int t = threadIdx.x;
    __shared__ float gs[HIDDEN];
    __shared__ float t1[HIDDEN];
    __shared__ float red[256];
    int lo = 0, hi = N_NODES;
    while (lo < hi) { int mid = (lo + hi) >> 1; if (bid[mid] < g) lo = mid + 1; else hi = mid; }
    const int start = lo;
    hi = N_NODES;
    while (lo < hi) { int mid = (lo + hi) >> 1; if (bid[mid] < g + 1) lo = mid + 1; else hi = mid; }
    float cnt = (float)(lo - start);
    cnt = cnt > 1.f ? cnt : 1.f;
    gs[t] = gsum[g * HIDDEN + t] / cnt;
    __syncthreads();
    float acc = b1[t];
    for (int k = 0; k < HIDDEN; k++) acc += gs[k] * W1[k * HIDDEN + t];
    t1[t] = acc > 0.f ? acc : 0.f;
    __syncthreads();
    float acc2 = b2[t];
    for (int k = 0; k < HIDDEN; k++) acc2 += t1[k] * W2[k * HIDDEN + t];
    red[t] = acc2 * acc2;
    __syncthreads();
    for (int s = 128; s > 0; s >>= 1) {
        if (t < s) red[t] += red[t + s];
        __syncthreads();
    }
    float norm = sqrtf(red[0]);
    norm = norm > 1e-12f ? norm : 1e-12f;
    out[g * HIDDEN + t] = acc2 / norm;
}

extern "C" void kernel_launch(void* const* d_in, const int* in_sizes, int n_in,
                              void* d_out, int out_size, void* d_ws, size_t ws_size,
                              hipStream_t stream)
{
    const float* x   = (const float*)d_in[0];
    const int*   ei  = (const int*)d_in[1];
    const float* ea  = (const float*)d_in[2];
    const int*   bid = (const int*)d_in[3];
    const float* xW  = (const float*)d_in[4];
    const float* xb  = (const float*)d_in[5];
    const float* eW  = (const float*)d_in[6];
    const float* eb  = (const float*)d_in[7];
    const float* W1  = (const float*)d_in[8];
    const float* b1  = (const float*)d_in[9];
    const float* W2  = (const float*)d_in[10];
    const float* b2  = (const float*)d_in[11];
    const float* oW1 = (const float*)d_in[12];
    const float* ob1 = (const float*)d_in[13];
    const float* oW2 = (const float*)d_in[14];
    const float* ob2 = (const float*)d_in[15];
    float* out = (float*)d_out;

    // workspace layout (256B-aligned chunks)
    char* p = (char*)d_ws;
    auto alloc = [&](size_t bytes) { char* r = p; p += (bytes + 255) & ~(size_t)255; return r; };
    float* h     = (float*)alloc((size_t)N_NODES * HIDDEN * 4);
    float* z     = (float*)alloc((size_t)N_NODES * HIDDEN * 4);
    float* gpool = (float*)alloc((size_t)N_GRAPHS * HIDDEN * 4);
    int* deg     = (int*)alloc(N_NODES * 4);
    int* rowptr  = (int*)alloc((N_NODES + 1) * 4);
    int* cursor  = (int*)alloc(N_NODES * 4);
    int* bsum    = (int*)alloc(NBLK * 4);
    int* boff    = (int*)alloc(NBLK * 4);
    int* perm    = (int*)alloc((size_t)N_EDGES * 4);
    int* srcs    = (int*)alloc((size_t)N_EDGES * 4);
    int* dsts    = (int*)alloc((size_t)N_EDGES * 4);
    unsigned short* hbf = (unsigned short*)alloc((size_t)N_NODES * HIDDEN * 2);
    unsigned short* eab = (unsigned short*)alloc((size_t)N_EDGES * EDGE_DIM * 2);
    unsigned short* eWs = (unsigned short*)alloc((size_t)LAYERS * EDGE_DIM * HIDDEN * 2);
    unsigned short* W1s = (unsigned short*)alloc((size_t)LAYERS * HIDDEN * HIDDEN * 2);
    unsigned short* W2s = (unsigned short*)alloc((size_t)LAYERS * HIDDEN * HIDDEN * 2);

    // CSR build + dst-sorted bf16 edge data (reused across layers)
    hipMemsetAsync(deg, 0, N_NODES * sizeof(int), stream);
    hipMemsetAsync(cursor, 0, N_NODES * sizeof(int), stream);
    hipMemsetAsync(gpool, 0, N_GRAPHS * HIDDEN * sizeof(float), stream);
    deg_kernel<<<(N_EDGES + 255) / 256, 256, 0, stream>>>(ei, deg);
    pscan_kernel<<<NBLK, 256, 0, stream>>>(deg, rowptr, bsum);
    bscan_kernel<<<1, 128, 0, stream>>>(bsum, boff);
    addoff_kernel<<<NBLK, 256, 0, stream>>>(rowptr, boff);
    scatter_kernel<<<(N_EDGES + 255) / 256, 256, 0, stream>>>(ei, rowptr, cursor, perm);
    permute_kernel<<<(N_EDGES * 8) / 256, 256, 0, stream>>>(ea, ei, perm, eab, srcs, dsts);
    for (int l = 0; l < LAYERS; l++) {
        swizzle_kernel<<<64, 256, 0, stream>>>(eW + (size_t)l * EDGE_DIM * HIDDEN,
                                               eWs + (size_t)l * EDGE_DIM * HIDDEN, 2);
        swizzle_kernel<<<256, 256, 0, stream>>>(W1 + (size_t)l * HIDDEN * HIDDEN,
                                                W1s + (size_t)l * HIDDEN * HIDDEN, 8);
        swizzle_kernel<<<256, 256, 0, stream>>>(W2 + (size_t)l * HIDDEN * HIDDEN,
                                                W2s + (size_t)l * HIDDEN * HIDDEN, 8);
    }

    node_proj_kernel<<<N_NODES / NPB, 256, 0, stream>>>(x, xW, xb, h, hbf, z);
    for (int l = 0; l < LAYERS; l++) {
        edge_mfma_kernel<<<N_EDGES / (EB * ET), 256, 0, stream>>>(
            eab, srcs, dsts, eWs + (size_t)l * EDGE_DIM * HIDDEN,
            eb + l * HIDDEN, hbf, z);
        mlp_mfma_kernel<<<N_NODES / 32, 256, 0, stream>>>(
            W1s + (size_t)l * HIDDEN * HIDDEN, b1 + l * HIDDEN,
            W2s + (size_t)l * HIDDEN * HIDDEN, b2 + l * HIDDEN, h, z, hbf);
    }
    pool_kernel<<<N_GRAPHS * PSPLIT, 256, 0, stream>>>(h, bid, gpool);
    head_kernel<<<N_GRAPHS, 256, 0, stream>>>(gpool, bid, oW1, ob1, oW2, ob2, out);
}